// Round 2
// baseline (968.342 us; speedup 1.0000x reference)
//
#include <hip/hip_runtime.h>

// Row-wise cosine similarity mean:
//   out = mean_i [ dot(A_i,B_i) / (max(||A_i||,eps) * max(||B_i||,eps)) ]
// A,B: (N=1048576, D=128) fp32. Memory-bound: 1.074 GB read, ~170us floor.

#define EPS 1e-12f
#define D 128

constexpr int BLOCKS  = 2048;
constexpr int THREADS = 256;   // 4 waves/block

__global__ __launch_bounds__(THREADS) void cos_partials(
    const float* __restrict__ A, const float* __restrict__ B,
    float* __restrict__ partials, int nrows)
{
    const int lane   = threadIdx.x & 63;
    const int wid    = threadIdx.x >> 6;              // wave in block
    const int half   = lane >> 5;                     // which row of the pair
    const int sub    = lane & 31;                     // lane within 32-lane half
    const int gwave  = blockIdx.x * (THREADS >> 6) + wid;
    const int twaves = gridDim.x * (THREADS >> 6);
    const int npairs = nrows >> 1;

    float acc = 0.0f;

    for (int pair = gwave; pair < npairs; pair += twaves) {
        const size_t row = (size_t)pair * 2 + half;
        const float4 av = ((const float4*)(A + row * D))[sub];
        const float4 bv = ((const float4*)(B + row * D))[sub];

        float dab = av.x * bv.x + av.y * bv.y + av.z * bv.z + av.w * bv.w;
        float daa = av.x * av.x + av.y * av.y + av.z * av.z + av.w * av.w;
        float dbb = bv.x * bv.x + bv.y * bv.y + bv.z * bv.z + bv.w * bv.w;

        // butterfly over the 32-lane half (xor offsets < 32 never cross halves)
        #pragma unroll
        for (int off = 1; off <= 16; off <<= 1) {
            dab += __shfl_xor(dab, off, 64);
            daa += __shfl_xor(daa, off, 64);
            dbb += __shfl_xor(dbb, off, 64);
        }

        if (sub == 0) {
            const float c = dab / fmaxf(sqrtf(daa), EPS) / fmaxf(sqrtf(dbb), EPS);
            acc += c;
        }
    }

    // full-wave reduce (only lanes 0 and 32 hold nonzero acc)
    #pragma unroll
    for (int off = 1; off <= 32; off <<= 1) acc += __shfl_xor(acc, off, 64);

    __shared__ float wsum[THREADS >> 6];
    if (lane == 0) wsum[wid] = acc;
    __syncthreads();
    if (threadIdx.x == 0) {
        float s = 0.f;
        #pragma unroll
        for (int w = 0; w < (THREADS >> 6); ++w) s += wsum[w];
        partials[blockIdx.x] = s;
    }
}

__global__ __launch_bounds__(256) void final_reduce(
    const float* __restrict__ partials, float* __restrict__ out,
    int n, double invN)
{
    __shared__ double tsum[256];
    double acc = 0.0;
    for (int i = threadIdx.x; i < n; i += blockDim.x) acc += (double)partials[i];
    tsum[threadIdx.x] = acc;
    __syncthreads();

    // tree-reduce in LDS
    for (int s = 128; s > 0; s >>= 1) {
        if (threadIdx.x < s) tsum[threadIdx.x] += tsum[threadIdx.x + s];
        __syncthreads();
    }
    if (threadIdx.x == 0) out[0] = (float)(tsum[0] * invN);
}

extern "C" void kernel_launch(void* const* d_in, const int* in_sizes, int n_in,
                              void* d_out, int out_size, void* d_ws, size_t ws_size,
                              hipStream_t stream) {
    const float* A = (const float*)d_in[0];
    const float* B = (const float*)d_in[1];
    float* out = (float*)d_out;
    float* partials = (float*)d_ws;           // BLOCKS * 4 bytes

    const int nrows = in_sizes[0] / D;        // 1048576

    cos_partials<<<BLOCKS, THREADS, 0, stream>>>(A, B, partials, nrows);
    final_reduce<<<1, 256, 0, stream>>>(partials, out, BLOCKS, 1.0 / (double)nrows);
}